// Round 1
// baseline (741.288 us; speedup 1.0000x reference)
//
#include <hip/hip_runtime.h>

typedef unsigned short ushort_t;
typedef __bf16 bf16x8 __attribute__((ext_vector_type(8)));
typedef float f32x4 __attribute__((ext_vector_type(4)));

#define NTOK 98
#define CDIM 128
#define LD   136            // LDS row stride in elements: 272B = 17 x 16B slots (odd -> conflict-free)
#define SM_TOTAL 156672     // 4*30464 + 34816 bytes

__device__ __forceinline__ ushort_t f2bf(float f) {
  unsigned u = __builtin_bit_cast(unsigned, f);
  u += 0x7fffu + ((u >> 16) & 1u);     // round-to-nearest-even
  return (ushort_t)(u >> 16);
}

struct alignas(8) us4 { ushort_t x, y, z, w; };

// ---------------- precompute: bf16 weight fragments + fused positional bias ----------------
__global__ void precompute_k(const float* __restrict__ qkv_w, const float* __restrict__ proj_w,
                             const float* __restrict__ bias_table, const int* __restrict__ rel_index,
                             ushort_t* __restrict__ wqkv, ushort_t* __restrict__ wproj,
                             float* __restrict__ bias_pre) {
  int t = blockIdx.x * blockDim.x + threadIdx.x;
  int stride = gridDim.x * blockDim.x;
  // qkv_w (128x384) -> fragment layout [nt(24)][kk(4)][lane(64)][j(8)] ; elem = W[kk*32+(lane>>4)*8+j][nt*16+(lane&15)]
  for (int g = t; g < 24 * 4 * 64; g += stride) {
    int nt = g >> 8, kk = (g >> 6) & 3, lane = g & 63;
    int n = nt * 16 + (lane & 15);
    int k0 = kk * 32 + (lane >> 4) * 8;
    ushort_t* dst = wqkv + g * 8;
#pragma unroll
    for (int j = 0; j < 8; ++j) dst[j] = f2bf(qkv_w[(k0 + j) * 384 + n]);
  }
  // proj_w (128x128) -> [nt(8)][kk(4)][lane][j]
  for (int g = t; g < 8 * 4 * 64; g += stride) {
    int nt = g >> 8, kk = (g >> 6) & 3, lane = g & 63;
    int n = nt * 16 + (lane & 15);
    int k0 = kk * 32 + (lane >> 4) * 8;
    ushort_t* dst = wproj + g * 8;
#pragma unroll
    for (int j = 0; j < 8; ++j) dst[j] = f2bf(proj_w[(k0 + j) * 128 + n]);
  }
  // bias_pre[h][i][j] = bias_table[rel_index[i][j]][h]
  for (int e = t; e < NTOK * NTOK; e += stride) {
    int idx = rel_index[e] * 4;
#pragma unroll
    for (int h = 0; h < 4; ++h) bias_pre[h * (NTOK * NTOK) + e] = bias_table[idx + h];
  }
}

// ---------------- fused window attention: one block per window ----------------
__launch_bounds__(512)
__global__ void wattn_k(const float* __restrict__ x, const float* __restrict__ mask,
                        const float* __restrict__ qkv_b, const float* __restrict__ proj_b,
                        const ushort_t* __restrict__ wqkv, const ushort_t* __restrict__ wproj,
                        const float* __restrict__ bias_pre, float* __restrict__ out) {
  extern __shared__ char smem[];
  ushort_t* const xb = (ushort_t*)smem;                  // [112][LD] bf16 x-tile; reused as P
  ushort_t* const Q  = (ushort_t*)(smem + 30464);        // [112][LD]  (cols 0..127 = 4 heads x 32, pre-scaled)
  ushort_t* const Kl = (ushort_t*)(smem + 60928);        // [112][LD]
  ushort_t* const O  = (ushort_t*)(smem + 91392);        // [112][LD]  attention output (bf16)
  ushort_t* const Vt = (ushort_t*)(smem + 121856);       // [128][LD]  V transposed: Vt[channel][token]

  const int b    = blockIdx.x;
  const int tid  = threadIdx.x;
  const int w    = tid >> 6;
  const int lane = tid & 63;
  const int l15  = lane & 15;
  const int l4   = lane >> 4;

  // ---- stage x -> bf16 LDS (zero rows 98..111, zero Vt token cols 112..127) ----
  const float* xw = x + (size_t)b * (NTOK * CDIM);
  for (int f = tid; f < NTOK * 32; f += 512) {
    int i = f >> 5, c4 = (f & 31) << 2;
    float4 v = *(const float4*)(xw + i * CDIM + c4);
    us4 o; o.x = f2bf(v.x); o.y = f2bf(v.y); o.z = f2bf(v.z); o.w = f2bf(v.w);
    *(us4*)(xb + i * LD + c4) = o;
  }
  {
    us4 z = {0, 0, 0, 0};
    for (int f = tid; f < 14 * 32; f += 512) {
      int i = NTOK + (f >> 5), c4 = (f & 31) << 2;
      *(us4*)(xb + i * LD + c4) = z;
    }
    for (int f = tid; f < 128 * 4; f += 512) {
      int ch = f >> 2, t4 = 112 + ((f & 3) << 2);
      *(us4*)(Vt + ch * LD + t4) = z;
    }
  }
  __syncthreads();

  // ---- phase 1: QKV = xb @ wqkv  (168 16x16 tiles, K=128) ----
  for (int t = w; t < 168; t += 8) {
    int mt = t % 7, nt = t / 7;
    int mb = mt << 4;
    f32x4 acc = {0.f, 0.f, 0.f, 0.f};
#pragma unroll
    for (int kk = 0; kk < 4; ++kk) {
      bf16x8 a  = *(const bf16x8*)(xb + (mb + l15) * LD + kk * 32 + l4 * 8);
      bf16x8 bw = *(const bf16x8*)(wqkv + (((nt << 2) + kk) * 64 + lane) * 8);
      acc = __builtin_amdgcn_mfma_f32_16x16x32_bf16(a, bw, acc, 0, 0, 0);
    }
    int n = (nt << 4) + l15;
    float bias = qkv_b[n];
    int r0 = mb + (l4 << 2);
    if (nt < 8) {                     // Q, pre-scaled by hd^-0.5
#pragma unroll
      for (int j = 0; j < 4; ++j)
        Q[(r0 + j) * LD + n] = f2bf((acc[j] + bias) * 0.17677669529663687f);
    } else if (nt < 16) {             // K
      int c = n - 128;
#pragma unroll
      for (int j = 0; j < 4; ++j)
        Kl[(r0 + j) * LD + c] = f2bf(acc[j] + bias);
    } else {                          // V -> transposed store (4 consecutive tokens per lane)
      int c = n - 256;
      us4 o; o.x = f2bf(acc[0] + bias); o.y = f2bf(acc[1] + bias);
             o.z = f2bf(acc[2] + bias); o.w = f2bf(acc[3] + bias);
      *(us4*)(Vt + c * LD + r0) = o;
    }
  }
  __syncthreads();

  // ---- phase 2: per-head attention; wave w owns query m-tile w (w<7) ----
  ushort_t* const P = xb;
  const float* maskw = mask + (size_t)(b & 63) * (NTOK * NTOK);
  if (w < 7) {
    const int mb = w << 4;
    {  // zero P token cols 112..127 of own rows (once; heads only rewrite cols 0..111)
      us4 z = {0, 0, 0, 0};
      int r = mb + (lane >> 2), t4 = 112 + ((lane & 3) << 2);
      *(us4*)(P + r * LD + t4) = z;
    }
    const int rowA = mb + l15;
#pragma unroll 1
    for (int h = 0; h < 4; ++h) {
      bf16x8 aq = *(const bf16x8*)(Q + rowA * LD + h * 32 + l4 * 8);
      f32x4 s[7];
#pragma unroll
      for (int nt = 0; nt < 7; ++nt) {
        bf16x8 bk = *(const bf16x8*)(Kl + ((nt << 4) + l15) * LD + h * 32 + l4 * 8);
        f32x4 z4 = {0.f, 0.f, 0.f, 0.f};
        s[nt] = __builtin_amdgcn_mfma_f32_16x16x32_bf16(aq, bk, z4, 0, 0, 0);
      }
      // bias + mask, key-padding mask, row max
      float rmax[4] = {-1e30f, -1e30f, -1e30f, -1e30f};
#pragma unroll
      for (int nt = 0; nt < 7; ++nt) {
        int jc = (nt << 4) + l15;
#pragma unroll
        for (int j = 0; j < 4; ++j) {
          int i = mb + (l4 << 2) + j;
          float v;
          if (jc < NTOK) {
            float add = 0.f;
            if (i < NTOK) add = bias_pre[h * (NTOK * NTOK) + i * NTOK + jc] + maskw[i * NTOK + jc];
            v = s[nt][j] + add;
          } else v = -1e30f;
          s[nt][j] = v;
          rmax[j] = fmaxf(rmax[j], v);
        }
      }
#pragma unroll
      for (int j = 0; j < 4; ++j) {
        rmax[j] = fmaxf(rmax[j], __shfl_xor(rmax[j], 1, 64));
        rmax[j] = fmaxf(rmax[j], __shfl_xor(rmax[j], 2, 64));
        rmax[j] = fmaxf(rmax[j], __shfl_xor(rmax[j], 4, 64));
        rmax[j] = fmaxf(rmax[j], __shfl_xor(rmax[j], 8, 64));
      }
      float rsum[4] = {0.f, 0.f, 0.f, 0.f};
#pragma unroll
      for (int nt = 0; nt < 7; ++nt)
#pragma unroll
        for (int j = 0; j < 4; ++j) {
          float p = __expf(s[nt][j] - rmax[j]);
          s[nt][j] = p;
          rsum[j] += p;
        }
#pragma unroll
      for (int j = 0; j < 4; ++j) {
        rsum[j] += __shfl_xor(rsum[j], 1, 64);
        rsum[j] += __shfl_xor(rsum[j], 2, 64);
        rsum[j] += __shfl_xor(rsum[j], 4, 64);
        rsum[j] += __shfl_xor(rsum[j], 8, 64);
      }
      float inv[4];
#pragma unroll
      for (int j = 0; j < 4; ++j) inv[j] = 1.f / rsum[j];
      // normalized P -> bf16 LDS (own rows only)
#pragma unroll
      for (int nt = 0; nt < 7; ++nt) {
        int jc = (nt << 4) + l15;
#pragma unroll
        for (int j = 0; j < 4; ++j)
          P[(mb + (l4 << 2) + j) * LD + jc] = f2bf(s[nt][j] * inv[j]);
      }
      // PV: O_tile = P(16x128) @ V(128x32)
#pragma unroll
      for (int no = 0; no < 2; ++no) {
        f32x4 acc = {0.f, 0.f, 0.f, 0.f};
#pragma unroll
        for (int kt = 0; kt < 4; ++kt) {
          bf16x8 ap = *(const bf16x8*)(P + rowA * LD + kt * 32 + l4 * 8);
          bf16x8 bv = *(const bf16x8*)(Vt + (h * 32 + (no << 4) + l15) * LD + kt * 32 + l4 * 8);
          acc = __builtin_amdgcn_mfma_f32_16x16x32_bf16(ap, bv, acc, 0, 0, 0);
        }
        int c = h * 32 + (no << 4) + l15;
#pragma unroll
        for (int j = 0; j < 4; ++j)
          O[(mb + (l4 << 2) + j) * LD + c] = f2bf(acc[j]);
      }
    }
  }
  __syncthreads();

  // ---- phase 3: out = O @ proj_w + proj_b ----
  float* outw = out + (size_t)b * (NTOK * CDIM);
  for (int t = w; t < 56; t += 8) {
    int mt = t % 7, nt = t / 7;
    int mb = mt << 4;
    f32x4 acc = {0.f, 0.f, 0.f, 0.f};
#pragma unroll
    for (int kk = 0; kk < 4; ++kk) {
      bf16x8 a  = *(const bf16x8*)(O + (mb + l15) * LD + kk * 32 + l4 * 8);
      bf16x8 bw = *(const bf16x8*)(wproj + (((nt << 2) + kk) * 64 + lane) * 8);
      acc = __builtin_amdgcn_mfma_f32_16x16x32_bf16(a, bw, acc, 0, 0, 0);
    }
    int n = (nt << 4) + l15;
    float pb = proj_b[n];
#pragma unroll
    for (int j = 0; j < 4; ++j) {
      int i = mb + (l4 << 2) + j;
      if (i < NTOK) outw[i * CDIM + n] = acc[j] + pb;
    }
  }
}

extern "C" void kernel_launch(void* const* d_in, const int* in_sizes, int n_in,
                              void* d_out, int out_size, void* d_ws, size_t ws_size,
                              hipStream_t stream) {
  const float* x        = (const float*)d_in[0];
  const float* mask     = (const float*)d_in[1];
  const float* qkv_w    = (const float*)d_in[2];
  const float* qkv_b    = (const float*)d_in[3];
  const float* proj_w   = (const float*)d_in[4];
  const float* proj_b   = (const float*)d_in[5];
  const float* bias_tab = (const float*)d_in[6];
  const int*   rel_idx  = (const int*)d_in[7];
  float* out = (float*)d_out;

  ushort_t* wqkv  = (ushort_t*)d_ws;                         //  98304 B
  ushort_t* wproj = (ushort_t*)((char*)d_ws + 98304);        //  32768 B
  float*    biasp = (float*)((char*)d_ws + 131072);          // 153664 B

  precompute_k<<<64, 256, 0, stream>>>(qkv_w, proj_w, bias_tab, rel_idx, wqkv, wproj, biasp);

  hipFuncSetAttribute(reinterpret_cast<const void*>(wattn_k),
                      hipFuncAttributeMaxDynamicSharedMemorySize, SM_TOTAL);
  wattn_k<<<4096, 512, SM_TOTAL, stream>>>(x, mask, qkv_b, proj_b, wqkv, wproj, biasp, out);
}

// Round 2
// 356.070 us; speedup vs baseline: 2.0819x; 2.0819x over previous
//
#include <hip/hip_runtime.h>

typedef unsigned short ushort_t;
typedef __bf16 bf16x8 __attribute__((ext_vector_type(8)));
typedef float f32x4 __attribute__((ext_vector_type(4)));

#define NTOK 98
#define CDIM 128
#define LD   136            // LDS row stride in elements: 272B = 17 x 16B slots (odd -> conflict-free)
#define PSLOT (16 * LD)     // per-wave P slot, elems (4352 B)
#define SM_TOTAL 156672     // 14*4352 + 3*30464 + 34816... see layout below

__device__ __forceinline__ ushort_t f2bf(float f) {
  unsigned u = __builtin_bit_cast(unsigned, f);
  u += 0x7fffu + ((u >> 16) & 1u);     // round-to-nearest-even
  return (ushort_t)(u >> 16);
}

struct alignas(8) us4 { ushort_t x, y, z, w; };

// ---------------- precompute: bf16 weight fragments + fused (bias+mask) table ----------------
__global__ void precompute_k(const float* __restrict__ qkv_w, const float* __restrict__ proj_w,
                             const float* __restrict__ bias_table, const int* __restrict__ rel_index,
                             const float* __restrict__ mask,
                             ushort_t* __restrict__ wqkv, ushort_t* __restrict__ wproj,
                             float* __restrict__ comb) {
  int t = blockIdx.x * blockDim.x + threadIdx.x;
  int stride = gridDim.x * blockDim.x;
  // qkv_w (128x384) -> fragment layout [nt(24)][kk(4)][lane(64)][j(8)] ; elem = W[kk*32+(lane>>4)*8+j][nt*16+(lane&15)]
  for (int g = t; g < 24 * 4 * 64; g += stride) {
    int nt = g >> 8, kk = (g >> 6) & 3, lane = g & 63;
    int n = nt * 16 + (lane & 15);
    int k0 = kk * 32 + (lane >> 4) * 8;
    ushort_t* dst = wqkv + g * 8;
#pragma unroll
    for (int j = 0; j < 8; ++j) dst[j] = f2bf(qkv_w[(k0 + j) * 384 + n]);
  }
  // proj_w (128x128) -> [nt(8)][kk(4)][lane][j]
  for (int g = t; g < 8 * 4 * 64; g += stride) {
    int nt = g >> 8, kk = (g >> 6) & 3, lane = g & 63;
    int n = nt * 16 + (lane & 15);
    int k0 = kk * 32 + (lane >> 4) * 8;
    ushort_t* dst = wproj + g * 8;
#pragma unroll
    for (int j = 0; j < 8; ++j) dst[j] = f2bf(proj_w[(k0 + j) * 128 + n]);
  }
  // comb[h][wm][i][j] = bias_table[rel_index[i][j]][h] + mask[wm][i][j]
  for (int e = t; e < 4 * 64 * NTOK * NTOK; e += stride) {
    int ij = e % (NTOK * NTOK);
    int hw = e / (NTOK * NTOK);
    int wm = hw & 63, h = hw >> 6;
    comb[e] = bias_table[rel_index[ij] * 4 + h] + mask[wm * (NTOK * NTOK) + ij];
  }
}

// ---------------- fused window attention: one block (1024 thr = 16 waves) per window ----------------
__launch_bounds__(1024)
__global__ void wattn_k(const float* __restrict__ x,
                        const float* __restrict__ qkv_b, const float* __restrict__ proj_b,
                        const ushort_t* __restrict__ wqkv, const ushort_t* __restrict__ wproj,
                        const float* __restrict__ comb, float* __restrict__ out) {
  extern __shared__ char smem[];
  // layout (bytes):
  //   0      .. 60928  : P region, 14 slots of [16][LD] bf16 (per phase-2 wave); aliased as xb [112][LD] in phase 1
  //   60928  .. 91392  : Q [112][LD] (pre-scaled, 4 heads x 32 cols); aliased as O in phase 2/3
  //   91392  .. 121856 : K [112][LD]
  //   121856 .. 156672 : Vt [128][LD]  (V transposed: Vt[channel][token])
  ushort_t* const Pb = (ushort_t*)smem;
  ushort_t* const xb = (ushort_t*)smem;
  ushort_t* const Q  = (ushort_t*)(smem + 60928);
  ushort_t* const Kl = (ushort_t*)(smem + 91392);
  ushort_t* const Vt = (ushort_t*)(smem + 121856);

  const int b    = blockIdx.x;
  const int tid  = threadIdx.x;
  const int w    = tid >> 6;
  const int lane = tid & 63;
  const int l15  = lane & 15;
  const int l4   = lane >> 4;

  // ---- stage x -> bf16 LDS (zero rows 98..111, zero Vt token cols 112..127) ----
  const float* xw = x + (size_t)b * (NTOK * CDIM);
  for (int f = tid; f < NTOK * 32; f += 1024) {
    int i = f >> 5, c4 = (f & 31) << 2;
    float4 v = *(const float4*)(xw + i * CDIM + c4);
    us4 o; o.x = f2bf(v.x); o.y = f2bf(v.y); o.z = f2bf(v.z); o.w = f2bf(v.w);
    *(us4*)(xb + i * LD + c4) = o;
  }
  {
    us4 z = {0, 0, 0, 0};
    for (int f = tid; f < 14 * 32; f += 1024) {
      int i = NTOK + (f >> 5), c4 = (f & 31) << 2;
      *(us4*)(xb + i * LD + c4) = z;
    }
    for (int f = tid; f < 128 * 4; f += 1024) {
      int ch = f >> 2, t4 = 112 + ((f & 3) << 2);
      *(us4*)(Vt + ch * LD + t4) = z;
    }
  }
  __syncthreads();

  // ---- phase 1: QKV = xb @ wqkv  (168 16x16 tiles, K=128) ----
  for (int t = w; t < 168; t += 16) {
    int mt = t % 7, nt = t / 7;
    int mb = mt << 4;
    f32x4 acc = {0.f, 0.f, 0.f, 0.f};
#pragma unroll
    for (int kk = 0; kk < 4; ++kk) {
      bf16x8 a  = *(const bf16x8*)(xb + (mb + l15) * LD + kk * 32 + l4 * 8);
      bf16x8 bw = *(const bf16x8*)(wqkv + (((nt << 2) + kk) * 64 + lane) * 8);
      acc = __builtin_amdgcn_mfma_f32_16x16x32_bf16(a, bw, acc, 0, 0, 0);
    }
    int n = (nt << 4) + l15;
    float bias = qkv_b[n];
    int r0 = mb + (l4 << 2);
    if (nt < 8) {                     // Q, pre-scaled by hd^-0.5
#pragma unroll
      for (int j = 0; j < 4; ++j)
        Q[(r0 + j) * LD + n] = f2bf((acc[j] + bias) * 0.17677669529663687f);
    } else if (nt < 16) {             // K
      int c = n - 128;
#pragma unroll
      for (int j = 0; j < 4; ++j)
        Kl[(r0 + j) * LD + c] = f2bf(acc[j] + bias);
    } else {                          // V -> transposed store (4 consecutive tokens per lane)
      int c = n - 256;
      us4 o; o.x = f2bf(acc[0] + bias); o.y = f2bf(acc[1] + bias);
             o.z = f2bf(acc[2] + bias); o.w = f2bf(acc[3] + bias);
      *(us4*)(Vt + c * LD + r0) = o;
    }
  }
  __syncthreads();

  // ---- phase 2: wave (m, head-group) owns query m-tile and 2 heads; private P slot ----
  if (w < 14) {
    const int m  = w % 7;
    const int hg = w / 7;
    const int mb = m << 4;
    ushort_t* const Pw = Pb + w * PSLOT;
    {  // zero P token cols 112..127 (own slot; heads only rewrite cols 0..111)
      us4 z = {0, 0, 0, 0};
      *(us4*)(Pw + (lane >> 2) * LD + 112 + ((lane & 3) << 2)) = z;
    }
    const int rowA = mb + l15;
    const float* combh = comb + (size_t)(b & 63) * (NTOK * NTOK);
#pragma unroll 1
    for (int h2 = 0; h2 < 2; ++h2) {
      const int h = hg * 2 + h2;
      const float* combw = combh + (size_t)h * (64 * NTOK * NTOK);
      bf16x8 aq = *(const bf16x8*)(Q + rowA * LD + h * 32 + l4 * 8);
      f32x4 s[7];
#pragma unroll
      for (int nt = 0; nt < 7; ++nt) {
        bf16x8 bk = *(const bf16x8*)(Kl + ((nt << 4) + l15) * LD + h * 32 + l4 * 8);
        f32x4 z4 = {0.f, 0.f, 0.f, 0.f};
        s[nt] = __builtin_amdgcn_mfma_f32_16x16x32_bf16(aq, bk, z4, 0, 0, 0);
      }
      // (bias+mask) add, key-padding mask, row max
      float rmax[4] = {-1e30f, -1e30f, -1e30f, -1e30f};
#pragma unroll
      for (int nt = 0; nt < 7; ++nt) {
        int jc = (nt << 4) + l15;
#pragma unroll
        for (int j = 0; j < 4; ++j) {
          int i = mb + (l4 << 2) + j;
          float v;
          if (jc < NTOK) {
            float add = (i < NTOK) ? combw[i * NTOK + jc] : 0.f;
            v = s[nt][j] + add;
          } else v = -1e30f;
          s[nt][j] = v;
          rmax[j] = fmaxf(rmax[j], v);
        }
      }
#pragma unroll
      for (int j = 0; j < 4; ++j) {
        rmax[j] = fmaxf(rmax[j], __shfl_xor(rmax[j], 1, 64));
        rmax[j] = fmaxf(rmax[j], __shfl_xor(rmax[j], 2, 64));
        rmax[j] = fmaxf(rmax[j], __shfl_xor(rmax[j], 4, 64));
        rmax[j] = fmaxf(rmax[j], __shfl_xor(rmax[j], 8, 64));
      }
      float rsum[4] = {0.f, 0.f, 0.f, 0.f};
#pragma unroll
      for (int nt = 0; nt < 7; ++nt)
#pragma unroll
        for (int j = 0; j < 4; ++j) {
          float p = __expf(s[nt][j] - rmax[j]);
          s[nt][j] = p;
          rsum[j] += p;
        }
#pragma unroll
      for (int j = 0; j < 4; ++j) {
        rsum[j] += __shfl_xor(rsum[j], 1, 64);
        rsum[j] += __shfl_xor(rsum[j], 2, 64);
        rsum[j] += __shfl_xor(rsum[j], 4, 64);
        rsum[j] += __shfl_xor(rsum[j], 8, 64);
      }
      float inv[4];
#pragma unroll
      for (int j = 0; j < 4; ++j) inv[j] = 1.f / rsum[j];
      // normalized P -> bf16 LDS (private slot, local rows 0..15)
#pragma unroll
      for (int nt = 0; nt < 7; ++nt) {
        int jc = (nt << 4) + l15;
#pragma unroll
        for (int j = 0; j < 4; ++j)
          Pw[((l4 << 2) + j) * LD + jc] = f2bf(s[nt][j] * inv[j]);
      }
      // PV: O_tile = P(16x128) @ V(128x32); O aliases Q (cols h*32.. only read by this wave)
#pragma unroll
      for (int no = 0; no < 2; ++no) {
        f32x4 acc = {0.f, 0.f, 0.f, 0.f};
#pragma unroll
        for (int kt = 0; kt < 4; ++kt) {
          bf16x8 ap = *(const bf16x8*)(Pw + l15 * LD + kt * 32 + l4 * 8);
          bf16x8 bv = *(const bf16x8*)(Vt + (h * 32 + (no << 4) + l15) * LD + kt * 32 + l4 * 8);
          acc = __builtin_amdgcn_mfma_f32_16x16x32_bf16(ap, bv, acc, 0, 0, 0);
        }
        int c = h * 32 + (no << 4) + l15;
#pragma unroll
        for (int j = 0; j < 4; ++j)
          Q[(mb + (l4 << 2) + j) * LD + c] = f2bf(acc[j]);
      }
    }
  }
  __syncthreads();

  // ---- phase 3: out = O @ proj_w + proj_b   (O lives in Q buffer) ----
  float* outw = out + (size_t)b * (NTOK * CDIM);
  for (int t = w; t < 56; t += 16) {
    int mt = t % 7, nt = t / 7;
    int mb = mt << 4;
    f32x4 acc = {0.f, 0.f, 0.f, 0.f};
#pragma unroll
    for (int kk = 0; kk < 4; ++kk) {
      bf16x8 a  = *(const bf16x8*)(Q + (mb + l15) * LD + kk * 32 + l4 * 8);
      bf16x8 bw = *(const bf16x8*)(wproj + (((nt << 2) + kk) * 64 + lane) * 8);
      acc = __builtin_amdgcn_mfma_f32_16x16x32_bf16(a, bw, acc, 0, 0, 0);
    }
    int n = (nt << 4) + l15;
    float pb = proj_b[n];
#pragma unroll
    for (int j = 0; j < 4; ++j) {
      int i = mb + (l4 << 2) + j;
      if (i < NTOK) outw[i * CDIM + n] = acc[j] + pb;
    }
  }
}

extern "C" void kernel_launch(void* const* d_in, const int* in_sizes, int n_in,
                              void* d_out, int out_size, void* d_ws, size_t ws_size,
                              hipStream_t stream) {
  const float* x        = (const float*)d_in[0];
  const float* mask     = (const float*)d_in[1];
  const float* qkv_w    = (const float*)d_in[2];
  const float* qkv_b    = (const float*)d_in[3];
  const float* proj_w   = (const float*)d_in[4];
  const float* proj_b   = (const float*)d_in[5];
  const float* bias_tab = (const float*)d_in[6];
  const int*   rel_idx  = (const int*)d_in[7];
  float* out = (float*)d_out;

  ushort_t* wqkv  = (ushort_t*)d_ws;                         //  98304 B
  ushort_t* wproj = (ushort_t*)((char*)d_ws + 98304);        //  32768 B
  float*    combp = (float*)((char*)d_ws + 131072);          // 4*64*98*98*4 = 9834496 B

  precompute_k<<<256, 256, 0, stream>>>(qkv_w, proj_w, bias_tab, rel_idx, mask, wqkv, wproj, combp);

  hipFuncSetAttribute(reinterpret_cast<const void*>(wattn_k),
                      hipFuncAttributeMaxDynamicSharedMemorySize, SM_TOTAL);
  wattn_k<<<4096, 1024, SM_TOTAL, stream>>>(x, qkv_b, proj_b, wqkv, wproj, combp, out);
}

// Round 3
// 314.079 us; speedup vs baseline: 2.3602x; 1.1337x over previous
//
#include <hip/hip_runtime.h>

typedef unsigned short ushort_t;
typedef __bf16 bf16x8 __attribute__((ext_vector_type(8)));
typedef __bf16 bf16x4 __attribute__((ext_vector_type(4)));
typedef float f32x4 __attribute__((ext_vector_type(4)));

#define NTOK 98
#define CDIM 128
#define LD   136            // LDS row stride in elements: 272B = 17 x 16B slots (~conflict-free)
#define PSLOT (16 * LD)     // per-wave P slot, elems (4352 B)
#define SM_TOTAL 156672
#define QSCALE 0.2550181952219662f   // hd^-0.5 * log2(e)
#define LOG2E  1.4426950408889634f

#if defined(__has_builtin)
#if __has_builtin(__builtin_amdgcn_exp2f)
#define EXP2F(x) __builtin_amdgcn_exp2f(x)
#else
#define EXP2F(x) exp2f(x)
#endif
#if __has_builtin(__builtin_amdgcn_rcpf)
#define RCPF(x) __builtin_amdgcn_rcpf(x)
#else
#define RCPF(x) (1.f / (x))
#endif
#else
#define EXP2F(x) exp2f(x)
#define RCPF(x) (1.f / (x))
#endif

// ---------------- precompute: bf16 weight fragments + transposed fused (bias+mask)*log2e table ----------------
__global__ void precompute_k(const float* __restrict__ qkv_w, const float* __restrict__ proj_w,
                             const float* __restrict__ bias_table, const int* __restrict__ rel_index,
                             const float* __restrict__ mask,
                             __bf16* __restrict__ wqkv, __bf16* __restrict__ wproj,
                             float* __restrict__ comb) {
  int t = blockIdx.x * blockDim.x + threadIdx.x;
  int stride = gridDim.x * blockDim.x;
  // qkv_w (128x384) -> fragment layout [nt(24)][kk(4)][lane(64)][j(8)] ; elem = W[kk*32+(lane>>4)*8+j][nt*16+(lane&15)]
  for (int g = t; g < 24 * 4 * 64; g += stride) {
    int nt = g >> 8, kk = (g >> 6) & 3, lane = g & 63;
    int n = nt * 16 + (lane & 15);
    int k0 = kk * 32 + (lane >> 4) * 8;
    __bf16* dst = wqkv + g * 8;
#pragma unroll
    for (int j = 0; j < 8; ++j) dst[j] = (__bf16)qkv_w[(k0 + j) * 384 + n];
  }
  // proj_w (128x128) -> [nt(8)][kk(4)][lane][j]
  for (int g = t; g < 8 * 4 * 64; g += stride) {
    int nt = g >> 8, kk = (g >> 6) & 3, lane = g & 63;
    int n = nt * 16 + (lane & 15);
    int k0 = kk * 32 + (lane >> 4) * 8;
    __bf16* dst = wproj + g * 8;
#pragma unroll
    for (int j = 0; j < 8; ++j) dst[j] = (__bf16)proj_w[(k0 + j) * 128 + n];
  }
  // comb[h][wm][jc(112)][i(112)] = (jc>=98) ? -1e30 : (i>=98) ? 0 : (bias + mask)*log2e
  for (int e = t; e < 4 * 64 * 112 * 112; e += stride) {
    int i  = e % 112;
    int jc = (e / 112) % 112;
    int hw = e / (112 * 112);
    int wm = hw & 63, h = hw >> 6;
    float v;
    if (jc >= NTOK) v = -1e30f;
    else if (i >= NTOK) v = 0.f;
    else v = (bias_table[rel_index[i * NTOK + jc] * 4 + h] + mask[wm * (NTOK * NTOK) + i * NTOK + jc]) * LOG2E;
    comb[e] = v;
  }
}

// ---------------- fused window attention: one block (1024 thr = 16 waves) per window ----------------
__launch_bounds__(1024)
__global__ void wattn_k(const float* __restrict__ x,
                        const float* __restrict__ qkv_b, const float* __restrict__ proj_b,
                        const __bf16* __restrict__ wqkv, const __bf16* __restrict__ wproj,
                        const float* __restrict__ comb, float* __restrict__ out) {
  extern __shared__ char smem[];
  // layout (bytes):
  //   0      .. 60928  : P region, 14 slots of [16][LD] bf16; aliased as xb [112][LD] in phase 1
  //   60928  .. 91392  : Q [112][LD] (pre-scaled by QSCALE); aliased as O in phase 2/3
  //   91392  .. 121856 : K [112][LD]
  //   121856 .. 156672 : Vt [128][LD]  (V transposed: Vt[channel][token])
  __bf16* const Pb = (__bf16*)smem;
  __bf16* const xb = (__bf16*)smem;
  __bf16* const Q  = (__bf16*)(smem + 60928);
  __bf16* const Kl = (__bf16*)(smem + 91392);
  __bf16* const Vt = (__bf16*)(smem + 121856);

  const int b    = blockIdx.x;
  const int tid  = threadIdx.x;
  const int w    = tid >> 6;
  const int lane = tid & 63;
  const int l15  = lane & 15;
  const int l4   = lane >> 4;

  // ---- stage x -> bf16 LDS (zero rows 98..111, zero Vt token cols 112..127) ----
  const float* xw = x + (size_t)b * (NTOK * CDIM);
  for (int f = tid; f < NTOK * 32; f += 1024) {
    int i = f >> 5, c4 = (f & 31) << 2;
    float4 v = *(const float4*)(xw + i * CDIM + c4);
    bf16x4 o; o[0] = (__bf16)v.x; o[1] = (__bf16)v.y; o[2] = (__bf16)v.z; o[3] = (__bf16)v.w;
    *(bf16x4*)(xb + i * LD + c4) = o;
  }
  {
    bf16x4 z = {(__bf16)0.f, (__bf16)0.f, (__bf16)0.f, (__bf16)0.f};
    for (int f = tid; f < 14 * 32; f += 1024) {
      int i = NTOK + (f >> 5), c4 = (f & 31) << 2;
      *(bf16x4*)(xb + i * LD + c4) = z;
    }
    for (int f = tid; f < 128 * 4; f += 1024) {
      int ch = f >> 2, t4 = 112 + ((f & 3) << 2);
      *(bf16x4*)(Vt + ch * LD + t4) = z;
    }
  }
  __syncthreads();

  // ---- phase 1: QKV = xb @ wqkv  (168 16x16 tiles, K=128) ----
  for (int t = w; t < 168; t += 16) {
    int mt = t % 7, nt = t / 7;
    int mb = mt << 4;
    f32x4 acc = {0.f, 0.f, 0.f, 0.f};
#pragma unroll
    for (int kk = 0; kk < 4; ++kk) {
      bf16x8 a  = *(const bf16x8*)(xb + (mb + l15) * LD + kk * 32 + l4 * 8);
      bf16x8 bw = *(const bf16x8*)(wqkv + (((nt << 2) + kk) * 64 + lane) * 8);
      acc = __builtin_amdgcn_mfma_f32_16x16x32_bf16(a, bw, acc, 0, 0, 0);
    }
    int n = (nt << 4) + l15;
    float bias = qkv_b[n];
    int r0 = mb + (l4 << 2);
    if (nt < 8) {                     // Q, pre-scaled by hd^-0.5 * log2e
#pragma unroll
      for (int j = 0; j < 4; ++j)
        Q[(r0 + j) * LD + n] = (__bf16)((acc[j] + bias) * QSCALE);
    } else if (nt < 16) {             // K
      int c = n - 128;
#pragma unroll
      for (int j = 0; j < 4; ++j)
        Kl[(r0 + j) * LD + c] = (__bf16)(acc[j] + bias);
    } else {                          // V -> transposed store (4 consecutive tokens per lane)
      int c = n - 256;
      bf16x4 o; o[0] = (__bf16)(acc[0] + bias); o[1] = (__bf16)(acc[1] + bias);
                o[2] = (__bf16)(acc[2] + bias); o[3] = (__bf16)(acc[3] + bias);
      *(bf16x4*)(Vt + c * LD + r0) = o;
    }
  }
  __syncthreads();

  // ---- phase 2: wave (m, head-group) owns query m-tile and 2 heads; private P slot ----
  if (w < 14) {
    const int m  = w % 7;
    const int hg = w / 7;
    const int mb = m << 4;
    __bf16* const Pw = Pb + w * PSLOT;
    {  // zero P token cols 112..127 (own slot; heads only rewrite cols 0..111)
      bf16x4 z = {(__bf16)0.f, (__bf16)0.f, (__bf16)0.f, (__bf16)0.f};
      *(bf16x4*)(Pw + (lane >> 2) * LD + 112 + ((lane & 3) << 2)) = z;
    }
    const int rowA = mb + l15;
    const int i0   = mb + (l4 << 2);
#pragma unroll 2
    for (int h2 = 0; h2 < 2; ++h2) {
      const int h = hg * 2 + h2;
      const float* combw = comb + ((size_t)(h * 64 + (b & 63))) * (112 * 112);
      bf16x8 aq = *(const bf16x8*)(Q + rowA * LD + h * 32 + l4 * 8);
      f32x4 s[7];
#pragma unroll
      for (int nt = 0; nt < 7; ++nt) {
        f32x4 c4 = *(const f32x4*)(combw + ((nt << 4) + l15) * 112 + i0);
        bf16x8 bk = *(const bf16x8*)(Kl + ((nt << 4) + l15) * LD + h * 32 + l4 * 8);
        s[nt] = __builtin_amdgcn_mfma_f32_16x16x32_bf16(aq, bk, c4, 0, 0, 0);
      }
      // unnormalized softmax: p = exp2(s'), accumulate row sums
      float rsum[4] = {0.f, 0.f, 0.f, 0.f};
#pragma unroll
      for (int nt = 0; nt < 7; ++nt)
#pragma unroll
        for (int j = 0; j < 4; ++j) {
          float p = EXP2F(s[nt][j]);
          s[nt][j] = p;
          rsum[j] += p;
        }
      // store P_un (bf16 range == fp32 exponent range, safe unnormalized)
#pragma unroll
      for (int nt = 0; nt < 7; ++nt) {
        int jc = (nt << 4) + l15;
#pragma unroll
        for (int j = 0; j < 4; ++j)
          Pw[((l4 << 2) + j) * LD + jc] = (__bf16)s[nt][j];
      }
#pragma unroll
      for (int j = 0; j < 4; ++j) {
        rsum[j] += __shfl_xor(rsum[j], 1, 64);
        rsum[j] += __shfl_xor(rsum[j], 2, 64);
        rsum[j] += __shfl_xor(rsum[j], 4, 64);
        rsum[j] += __shfl_xor(rsum[j], 8, 64);
      }
      float inv[4];
#pragma unroll
      for (int j = 0; j < 4; ++j) inv[j] = RCPF(rsum[j]);
      // PV: O_tile = P(16x128) @ V(128x32), then normalize; O aliases Q (cols h*32.. only this wave)
#pragma unroll
      for (int no = 0; no < 2; ++no) {
        f32x4 acc = {0.f, 0.f, 0.f, 0.f};
#pragma unroll
        for (int kt = 0; kt < 4; ++kt) {
          bf16x8 ap = *(const bf16x8*)(Pw + l15 * LD + kt * 32 + l4 * 8);
          bf16x8 bv = *(const bf16x8*)(Vt + (h * 32 + (no << 4) + l15) * LD + kt * 32 + l4 * 8);
          acc = __builtin_amdgcn_mfma_f32_16x16x32_bf16(ap, bv, acc, 0, 0, 0);
        }
        int c = h * 32 + (no << 4) + l15;
#pragma unroll
        for (int j = 0; j < 4; ++j)
          Q[(mb + (l4 << 2) + j) * LD + c] = (__bf16)(acc[j] * inv[j]);
      }
    }
  }
  __syncthreads();

  // ---- phase 3: out = O @ proj_w + proj_b   (O lives in Q buffer) ----
  float* outw = out + (size_t)b * (NTOK * CDIM);
  for (int t = w; t < 56; t += 16) {
    int mt = t % 7, nt = t / 7;
    int mb = mt << 4;
    f32x4 acc = {0.f, 0.f, 0.f, 0.f};
#pragma unroll
    for (int kk = 0; kk < 4; ++kk) {
      bf16x8 a  = *(const bf16x8*)(Q + (mb + l15) * LD + kk * 32 + l4 * 8);
      bf16x8 bw = *(const bf16x8*)(wproj + (((nt << 2) + kk) * 64 + lane) * 8);
      acc = __builtin_amdgcn_mfma_f32_16x16x32_bf16(a, bw, acc, 0, 0, 0);
    }
    int n = (nt << 4) + l15;
    float pb = proj_b[n];
#pragma unroll
    for (int j = 0; j < 4; ++j) {
      int i = mb + (l4 << 2) + j;
      if (i < NTOK) outw[i * CDIM + n] = acc[j] + pb;
    }
  }
}

extern "C" void kernel_launch(void* const* d_in, const int* in_sizes, int n_in,
                              void* d_out, int out_size, void* d_ws, size_t ws_size,
                              hipStream_t stream) {
  const float* x        = (const float*)d_in[0];
  const float* mask     = (const float*)d_in[1];
  const float* qkv_w    = (const float*)d_in[2];
  const float* qkv_b    = (const float*)d_in[3];
  const float* proj_w   = (const float*)d_in[4];
  const float* proj_b   = (const float*)d_in[5];
  const float* bias_tab = (const float*)d_in[6];
  const int*   rel_idx  = (const int*)d_in[7];
  float* out = (float*)d_out;

  __bf16* wqkv  = (__bf16*)d_ws;                        //  98304 B
  __bf16* wproj = (__bf16*)((char*)d_ws + 98304);       //  32768 B
  float*  combp = (float*)((char*)d_ws + 131072);       //  4*64*112*112*4 = 12845056 B

  precompute_k<<<1024, 256, 0, stream>>>(qkv_w, proj_w, bias_tab, rel_idx, mask, wqkv, wproj, combp);

  hipFuncSetAttribute(reinterpret_cast<const void*>(wattn_k),
                      hipFuncAttributeMaxDynamicSharedMemorySize, SM_TOTAL);
  wattn_k<<<4096, 1024, SM_TOTAL, stream>>>(x, qkv_b, proj_b, wqkv, wproj, combp, out);
}